// Round 3
// baseline (266.127 us; speedup 1.0000x reference)
//
#include <hip/hip_runtime.h>
#include <math.h>

// EdgeEmbedding — persistent-block, software-pipelined form.
//
// Structural identity: edge_vec[e] = pair_vec[p] * orient[e], orient = +-1,
// 2 edges per pair => each edge reconstructs pair quantities locally
// (no atomics / gather).
//
// R2 change: instead of 11719 short-lived blocks (load->bar->compute->bar->
// store, HBM read latency + 2 barriers on every block critical path), launch
// <=1792 persistent blocks (7/CU, LDS-limited) that each own a CONTIGUOUS
// chunk of 256-edge tiles. Next tile's edge_vec/rev are prefetched into
// registers right after barrier B1 and consumed at the next iteration's LDS
// write — read latency hides under compute+store of the current tile, and
// store issue is continuous instead of bursty.
//
// All global I/O is coalesced: per-lane float4 (or contiguous dword).
// LDS strides 3 and 9 are coprime to 32 => <=2-way bank aliasing (free).
// Output stores are non-temporal (write-once data, keep out of L2).

#define TPB 256

typedef float f32x4 __attribute__((ext_vector_type(4)));

__global__ __launch_bounds__(TPB) void edge_kernel(const float* __restrict__ edge_vec,
                                                   const unsigned char* __restrict__ rev,
                                                   const float* __restrict__ coeffs,
                                                   float* __restrict__ out, int E,
                                                   int q, int rblk) {
    __shared__ float s_vec[TPB * 3];    // 3072 B
    __shared__ float s_emb[TPB * 9];    // 9216 B (stride 9, col 8 pad)
    __shared__ float s_attr[TPB * 9];   // 9216 B

    int t = threadIdx.x;
    int b = blockIdx.x;

    // contiguous tile chunk for this block (bijective split)
    long long tile    = (long long)b * q + (b < rblk ? b : rblk);
    long long tileEnd = tile + q + (b < rblk ? 1 : 0);

    // --- bool storage-width detect, once per block (first 4096 B of rev).
    // Any word > 1 => byte-packed numpy bools; else int32 storage.
    bool wide;
    {
        const uint4* rw = (const uint4*)rev;
        unsigned bad = 0;
        int lane = t & 63;
#pragma unroll
        for (int k = 0; k < 4; k++) {
            uint4 w = rw[lane + 64 * k];
            bad |= (w.x > 1u) | (w.y > 1u) | (w.z > 1u) | (w.w > 1u);
        }
        wide = !__any(bad);
    }

    // hoist bessel coeffs (8 floats, uniform)
    float cj[8];
#pragma unroll
    for (int j = 0; j < 8; j++) cj[j] = coeffs[j];

    const float4* gvec = (const float4*)edge_vec;
    const unsigned int* rev32 = (const unsigned int*)rev;
    f32x4* o4 = (f32x4*)out;
    long long embEnd4  = 9LL * E >> 2;
    long long attrEnd4 = 18LL * E >> 2;

    // --- preload first tile into registers
    float4 vreg = make_float4(0.f, 0.f, 0.f, 0.f);
    bool risrev = false;
    if (tile < tileEnd) {
        long long g4 = tile * 192 + t;
        if (t < 192 && 4 * g4 < 3LL * E) vreg = gvec[g4];
        long long e = tile * TPB + t;
        if (e < E) risrev = (wide ? rev32[e] : (unsigned)rev[e]) != 0;
    }

    for (; tile < tileEnd; ++tile) {
        // W: registers -> LDS (vmcnt wait on the prefetch lands here)
        if (t < 192) ((float4*)s_vec)[t] = vreg;
        bool isrev = risrev;
        __syncthreads();   // B1: prev tile's store-phase LDS reads + W done

        // P: prefetch next tile (consumed at next iteration's W)
        {
            long long nxt = tile + 1;
            if (nxt < tileEnd) {
                long long g4 = nxt * 192 + t;
                if (t < 192 && 4 * g4 < 3LL * E) vreg = gvec[g4];
                long long e = nxt * TPB + t;
                risrev = false;
                if (e < E) risrev = (wide ? rev32[e] : (unsigned)rev[e]) != 0;
            }
        }

        // C: compute this tile
        long long e = tile * TPB + t;
        bool valid = e < E;

        float o = isrev ? -1.0f : 1.0f;
        float px = s_vec[3 * t + 0] * o;
        float py = s_vec[3 * t + 1] * o;
        float pz = s_vec[3 * t + 2] * o;

        float r  = sqrtf(px * px + py * py + pz * pz);
        float rs = fmaxf(r, 1e-12f);

        // poly_cutoff p=6: 1 - 28 x^6 + 48 x^7 - 21 x^8, zero at x>=1
        float xr = r * 0.2f;                 // r / RC, RC=5
        float x3 = xr * xr * xr;
        float x6 = x3 * x3;
        float env = 1.0f - 28.0f * x6 + 48.0f * x6 * xr - 21.0f * x6 * xr * xr;
        env = (xr < 1.0f) ? env : 0.0f;

        float pref = 0.632455532034f / rs * env;   // sqrt(2/5)
#pragma unroll
        for (int j = 0; j < 8; j++)
            s_emb[9 * t + j] = pref * __sinf(cj[j] * xr);

        float ux = px / rs, uy = py / rs, uz = pz / rs;
        const float s3 = 1.73205080757f, s15 = 3.87298334621f, s5 = 2.2360679775f;
        float sh1 = s3 * ux, sh2 = s3 * uy, sh3 = s3 * uz;
        if (isrev) { sh1 = -sh1; sh2 = -sh2; sh3 = -sh3; }   // SH parity l=1
        s_attr[9 * t + 0] = 1.0f;
        s_attr[9 * t + 1] = sh1;
        s_attr[9 * t + 2] = sh2;
        s_attr[9 * t + 3] = sh3;
        s_attr[9 * t + 4] = s15 * ux * uy;
        s_attr[9 * t + 5] = s15 * uy * uz;
        s_attr[9 * t + 6] = 0.5f * s5 * (3.0f * uz * uz - 1.0f);
        s_attr[9 * t + 7] = s15 * ux * uz;
        s_attr[9 * t + 8] = 0.5f * s15 * (ux * ux - uy * uy);

        if (valid) __builtin_nontemporal_store(r, &out[e]);
        __syncthreads();   // B2: LDS staged

        // S: cooperative coalesced float4 stores (non-temporal)
        // edge_embedding region: floats [E, 9E); tile chunk = 512 f4
        long long embStart4 = ((long long)E >> 2) + tile * 512;
#pragma unroll
        for (int k = t; k < 512; k += TPB) {
            long long g4 = embStart4 + k;
            if (g4 < embEnd4) {
                int f0 = 4 * k;   // logical float idx within tile (stride-8 layout)
                f32x4 v;
                v.x = s_emb[9 * ((f0 + 0) >> 3) + ((f0 + 0) & 7)];
                v.y = s_emb[9 * ((f0 + 1) >> 3) + ((f0 + 1) & 7)];
                v.z = s_emb[9 * ((f0 + 2) >> 3) + ((f0 + 2) & 7)];
                v.w = s_emb[9 * ((f0 + 3) >> 3) + ((f0 + 3) & 7)];
                __builtin_nontemporal_store(v, &o4[g4]);
            }
        }

        // edge_attr region: floats [9E, 18E); tile chunk = 576 f4
        long long attrStart4 = (9LL * E >> 2) + tile * 576;
#pragma unroll
        for (int k = t; k < 576; k += TPB) {
            long long g4 = attrStart4 + k;
            if (g4 < attrEnd4) {
                f32x4 v = ((f32x4*)s_attr)[k];
                __builtin_nontemporal_store(v, &o4[g4]);
            }
        }
    }
}

extern "C" void kernel_launch(void* const* d_in, const int* in_sizes, int n_in,
                              void* d_out, int out_size, void* d_ws, size_t ws_size,
                              hipStream_t stream) {
    const float* edge_vec = (const float*)d_in[0];
    const float* coeffs   = (const float*)d_in[1];
    const unsigned char* rev = (const unsigned char*)d_in[3];

    int E = in_sizes[2];          // 2P edges
    float* out = (float*)d_out;

    int nTiles = (E + TPB - 1) / TPB;
    int grid = nTiles < 1792 ? nTiles : 1792;   // 7 blocks/CU (LDS-limited) x 256 CU
    int q = nTiles / grid;
    int rblk = nTiles % grid;

    edge_kernel<<<grid, TPB, 0, stream>>>(edge_vec, rev, coeffs, out, E, q, rblk);
}

// Round 4
// 257.194 us; speedup vs baseline: 1.0347x; 1.0347x over previous
//
#include <hip/hip_runtime.h>
#include <math.h>

// EdgeEmbedding — fully wave-independent, barrier-free form.
//
// Structural identity: edge_vec[e] = pair_vec[p] * orient[e], orient = +-1,
// 2 edges per pair => each edge reconstructs pair quantities locally
// (no atomics / gather).
//
// R4 changes vs R2 (best, 255.8):
//  * ZERO __syncthreads. Each wave owns a private LDS slice (192+576+576
//    floats); ds_write -> ds_read within one wave is ordered by lgkmcnt
//    (warp-synchronous idiom). Waves on a CU are free-running, so store
//    issue is continuous instead of block-synchronized bursts.
//  * One v_rcp_f32 replaces 4 IEEE divide sequences (rel err ~1e-7,
//    tolerance is 1.6e-2). sqrtf kept.
//  * All output f4 indices are 32-bit (18E/4 = 13.5M < 2^31): halves
//    address-calc VALU.
//  * nt stores kept (write-once output, bypass L2): R2 measured -5.6 us.
//
// Coalescing: edge_vec staged per-wave as 48 contiguous float4; emb stored
// via stride-9 LDS (2-way bank alias = free) and gathered to contiguous f4;
// attr slice is naturally contiguous (64 edges x 9 floats) -> ds_read_b128.

#define TPB 256

typedef float f32x4 __attribute__((ext_vector_type(4)));

__global__ __launch_bounds__(TPB) void edge_kernel(const float* __restrict__ edge_vec,
                                                   const unsigned char* __restrict__ rev,
                                                   const float* __restrict__ coeffs,
                                                   float* __restrict__ out, int E) {
    __shared__ float s_vec[4][192];     // per-wave: 48 f4 of edge_vec
    __shared__ float s_emb[4][576];     // per-wave: stride 9 (8 used + pad)
    __shared__ float s_attr[4][576];    // per-wave: 64 edges x 9, contiguous

    const int t    = threadIdx.x;
    const int wid  = t >> 6;
    const int lane = t & 63;
    const int e    = blockIdx.x * TPB + t;        // < 2^31
    const bool valid = e < E;
    const int we0  = blockIdx.x * TPB + (wid << 6);   // wave's first edge

    // --- bool storage-width detect (first 4096 B of rev, L2-hot).
    // Any word > 1 => byte-packed numpy bools; else int32 storage.
    bool wide;
    {
        const uint4* rw = (const uint4*)rev;
        unsigned bad = 0;
#pragma unroll
        for (int k = 0; k < 4; k++) {
            uint4 w = rw[lane + 64 * k];
            bad |= (w.x > 1u) | (w.y > 1u) | (w.z > 1u) | (w.w > 1u);
        }
        wide = !__any(bad);
    }

    // --- stage this wave's edge_vec chunk: 48 contiguous float4
    {
        const float4* gvec = (const float4*)edge_vec;
        if (lane < 48) {
            int g4 = ((we0 * 3) >> 2) + lane;     // we0*3 divisible by 4
            if (4 * g4 < 3 * E) ((float4*)s_vec[wid])[lane] = gvec[g4];
        }
    }
    bool isrev = valid &&
        ((wide ? ((const unsigned*)rev)[e] : (unsigned)rev[e]) != 0);

    // (compiler inserts lgkmcnt wait between the ds_write above and reads below;
    //  same-wave only -> no barrier)
    float o  = isrev ? -1.0f : 1.0f;
    float px = s_vec[wid][3 * lane + 0] * o;
    float py = s_vec[wid][3 * lane + 1] * o;
    float pz = s_vec[wid][3 * lane + 2] * o;

    float r    = sqrtf(px * px + py * py + pz * pz);
    float rs   = fmaxf(r, 1e-12f);
    float rinv = __builtin_amdgcn_rcpf(rs);       // v_rcp_f32, ~1 ulp

    // edge_length: contiguous dword store, issue early
    if (valid) __builtin_nontemporal_store(r, &out[e]);

    // poly_cutoff p=6: 1 - 28 x^6 + 48 x^7 - 21 x^8, zero at x>=1
    float xr = r * 0.2f;                           // r / RC, RC=5
    float x3 = xr * xr * xr;
    float x6 = x3 * x3;
    float env = 1.0f - 28.0f * x6 + 48.0f * x6 * xr - 21.0f * x6 * xr * xr;
    env = (xr < 1.0f) ? env : 0.0f;

    float pref = 0.632455532034f * rinv * env;     // sqrt(2/5)
#pragma unroll
    for (int j = 0; j < 8; j++)
        s_emb[wid][9 * lane + j] = pref * __sinf(coeffs[j] * xr);

    float ux = px * rinv, uy = py * rinv, uz = pz * rinv;
    const float s3 = 1.73205080757f, s15 = 3.87298334621f, s5 = 2.2360679775f;
    float sh1 = s3 * ux, sh2 = s3 * uy, sh3 = s3 * uz;
    if (isrev) { sh1 = -sh1; sh2 = -sh2; sh3 = -sh3; }   // SH parity on l=1
    s_attr[wid][9 * lane + 0] = 1.0f;
    s_attr[wid][9 * lane + 1] = sh1;
    s_attr[wid][9 * lane + 2] = sh2;
    s_attr[wid][9 * lane + 3] = sh3;
    s_attr[wid][9 * lane + 4] = s15 * ux * uy;
    s_attr[wid][9 * lane + 5] = s15 * uy * uz;
    s_attr[wid][9 * lane + 6] = 0.5f * s5 * (3.0f * uz * uz - 1.0f);
    s_attr[wid][9 * lane + 7] = s15 * ux * uz;
    s_attr[wid][9 * lane + 8] = 0.5f * s15 * (ux * ux - uy * uy);

    // --- per-wave coalesced nt stores (lgkmcnt orders LDS reads after writes)
    f32x4* o4 = (f32x4*)out;

    // edge_embedding region: floats [E, 9E); wave chunk = 512 floats = 128 f4
    {
        int embB4   = (E >> 2) + (we0 << 1);
        int embEnd4 = (9 * E) >> 2;
#pragma unroll
        for (int kk = 0; kk < 2; kk++) {
            int k  = lane + (kk << 6);
            int g4 = embB4 + k;
            if (g4 < embEnd4) {
                int f0 = k << 2;   // logical float idx in chunk (stride-8 layout)
                f32x4 v;
                v.x = s_emb[wid][9 * ((f0 + 0) >> 3) + ((f0 + 0) & 7)];
                v.y = s_emb[wid][9 * ((f0 + 1) >> 3) + ((f0 + 1) & 7)];
                v.z = s_emb[wid][9 * ((f0 + 2) >> 3) + ((f0 + 2) & 7)];
                v.w = s_emb[wid][9 * ((f0 + 3) >> 3) + ((f0 + 3) & 7)];
                __builtin_nontemporal_store(v, &o4[g4]);
            }
        }
    }

    // edge_attr region: floats [9E, 18E); wave chunk = 576 floats = 144 f4
    {
        int attrB4   = ((9 * E) >> 2) + ((9 * we0) >> 2);   // 9*we0 div by 4
        int attrEnd4 = (18 * E) >> 2;                       // 13.5M < 2^31
#pragma unroll
        for (int kk = 0; kk < 3; kk++) {
            int k = lane + (kk << 6);
            if (k < 144) {
                int g4 = attrB4 + k;
                if (g4 < attrEnd4) {
                    f32x4 v = ((f32x4*)s_attr[wid])[k];
                    __builtin_nontemporal_store(v, &o4[g4]);
                }
            }
        }
    }
}

extern "C" void kernel_launch(void* const* d_in, const int* in_sizes, int n_in,
                              void* d_out, int out_size, void* d_ws, size_t ws_size,
                              hipStream_t stream) {
    const float* edge_vec = (const float*)d_in[0];
    const float* coeffs   = (const float*)d_in[1];
    const unsigned char* rev = (const unsigned char*)d_in[3];

    int E = in_sizes[2];          // 2P edges
    float* out = (float*)d_out;

    int eblocks = (E + TPB - 1) / TPB;
    edge_kernel<<<eblocks, TPB, 0, stream>>>(edge_vec, rev, coeffs, out, E);
}